// Round 2
// baseline (84.384 us; speedup 1.0000x reference)
//
#include <hip/hip_runtime.h>
#include <hip/hip_bf16.h>

#define BATCH 65536
#define INF   64
#define OUTF  256
#define NMAT  15

typedef __bf16 bf16x8 __attribute__((ext_vector_type(8)));
typedef float  f32x4  __attribute__((ext_vector_type(4)));

__device__ __forceinline__ unsigned short f2bf(float f) {
    unsigned int u = __float_as_uint(f);
    unsigned int r = (u + 0x7FFFu + ((u >> 16) & 1u)) >> 16;
    return (unsigned short)r;
}

// Build combined bf16 weights wc[15][256][64] in streaming combine order:
// slot: 0=d1t, 1=d1_0, 2=M0, 3=d1_1, 4=M1, 5=M2, 6=d1_2, 7=M3, 8=M4, 9=M5,
//       10=d1_3, 11=M6, 12=M7, 13=M8, 14=M9   (M_p = dn_w2[p] * dn_w1[p][None,:])
__global__ void build_weights(const float* __restrict__ d1t_w,
                              const float* __restrict__ d1_w,
                              const float* __restrict__ dn_w1,
                              const float* __restrict__ dn_w2,
                              unsigned short* __restrict__ wc) {
    int idx = blockIdx.x * blockDim.x + threadIdx.x;
    if (idx >= NMAT * OUTF * INF) return;
    int slot = idx / (OUTF * INF);
    int rem  = idx - slot * (OUTF * INF);   // o*64 + i
    int i    = rem & (INF - 1);

    const signed char kind[NMAT] = {0,1,2,1,2,2,1,2,2,2,1,2,2,2,2};
    const signed char sidx[NMAT] = {0,0,0,1,1,2,2,3,4,5,3,6,7,8,9};

    int k = kind[slot], si = sidx[slot];
    float v;
    if (k == 0)      v = d1t_w[rem];
    else if (k == 1) v = d1_w[si * OUTF * INF + rem];
    else             v = dn_w2[si * OUTF * INF + rem] * dn_w1[si * INF + i];
    wc[idx] = f2bf(v);
}

// 512 threads = 8 waves per block; block owns 64 rows x 256 cols.
// Each wave owns 32 cols (2 col-frags of 16). Grid stays 1024 blocks so the
// 480 KiB combined-weight set is re-read from L2 only 1024x (~491 MB total),
// while occupancy cap rises from 16 to 32 waves/CU.
__global__ __launch_bounds__(512) void taylor_kernel(
    const float* __restrict__ x, const float* __restrict__ d0,
    const unsigned short* __restrict__ wc, float* __restrict__ out)
{
    const int lane = threadIdx.x & 63;
    const int wave = threadIdx.x >> 6;      // 0..7
    const int l15  = lane & 15;
    const int g    = lane >> 4;             // k-group 0..3
    const int row_base = blockIdx.x * 64;

    // A fragments: a[rf][s] covers rows [row_base+rf*16, +16), k = s*32 + g*8 + j
    bf16x8 a[4][2];
#pragma unroll
    for (int rf = 0; rf < 4; ++rf) {
        const float* xp = x + (size_t)(row_base + rf * 16 + l15) * INF;
#pragma unroll
        for (int s = 0; s < 2; ++s) {
            const int k0 = s * 32 + g * 8;
            f32x4 v0 = *(const f32x4*)(xp + k0);
            f32x4 v1 = *(const f32x4*)(xp + k0 + 4);
            bf16x8 fr;
#pragma unroll
            for (int j = 0; j < 4; ++j) { fr[j] = (__bf16)v0[j]; fr[4 + j] = (__bf16)v1[j]; }
            a[rf][s] = fr;
        }
    }

    // per-pass combine op: 0 = res=d0+y, 1 = tmp=y, 2 = tmp*=y, 3 = tmp*=y; res+=tmp
    constexpr int OPS[NMAT] = {0,1,3,1,2,3,1,2,2,3,1,2,2,2,3};

#pragma unroll 1
    for (int cf = 0; cf < 2; ++cf) {
        const int col = wave * 32 + cf * 16 + l15;
        const float d0v = d0[col];
        f32x4 res[4], tmp[4];

#pragma unroll
        for (int w = 0; w < NMAT; ++w) {
            const unsigned short* wp = wc + ((size_t)w * OUTF + col) * INF;
            bf16x8 b0 = *(const bf16x8*)(wp + g * 8);
            bf16x8 b1 = *(const bf16x8*)(wp + 32 + g * 8);
#pragma unroll
            for (int rf = 0; rf < 4; ++rf) {
                f32x4 y = {0.f, 0.f, 0.f, 0.f};
                y = __builtin_amdgcn_mfma_f32_16x16x32_bf16(a[rf][0], b0, y, 0, 0, 0);
                y = __builtin_amdgcn_mfma_f32_16x16x32_bf16(a[rf][1], b1, y, 0, 0, 0);
                if (OPS[w] == 0) {
                    f32x4 t = y;
#pragma unroll
                    for (int j = 0; j < 4; ++j) t[j] += d0v;
                    res[rf] = t;
                } else if (OPS[w] == 1) {
                    tmp[rf] = y;
                } else {
                    tmp[rf] = tmp[rf] * y;
                    if (OPS[w] == 3) res[rf] = res[rf] + tmp[rf];
                }
            }
        }

        // C layout: row = (lane>>4)*4 + r, col = lane&15
#pragma unroll
        for (int rf = 0; rf < 4; ++rf) {
            const int r0 = row_base + rf * 16 + g * 4;
#pragma unroll
            for (int r = 0; r < 4; ++r)
                out[(size_t)(r0 + r) * OUTF + col] = res[rf][r];
        }
    }
}

extern "C" void kernel_launch(void* const* d_in, const int* in_sizes, int n_in,
                              void* d_out, int out_size, void* d_ws, size_t ws_size,
                              hipStream_t stream) {
    const float* x    = (const float*)d_in[0];
    const float* d0   = (const float*)d_in[1];
    const float* d1t  = (const float*)d_in[2];
    const float* d1w  = (const float*)d_in[3];
    const float* dnw1 = (const float*)d_in[4];
    const float* dnw2 = (const float*)d_in[5];
    unsigned short* wc = (unsigned short*)d_ws;   // needs 15*256*64*2 = 480 KiB
    float* out = (float*)d_out;

    build_weights<<<(NMAT * OUTF * INF + 255) / 256, 256, 0, stream>>>(d1t, d1w, dnw1, dnw2, wc);
    taylor_kernel<<<BATCH / 64, 512, 0, stream>>>(x, d0, wc, out);
}

// Round 3
// 52.276 us; speedup vs baseline: 1.6142x; 1.6142x over previous
//
#include <hip/hip_runtime.h>
#include <hip/hip_bf16.h>

#define BATCH 65536
#define INF   64
#define OUTF  256
#define NMAT  15
#define RPB   512   // rows per block

typedef __bf16 bf16x8 __attribute__((ext_vector_type(8)));
typedef float  f32x4  __attribute__((ext_vector_type(4)));

__device__ __forceinline__ unsigned short f2bf(float f) {
    unsigned int u = __float_as_uint(f);
    unsigned int r = (u + 0x7FFFu + ((u >> 16) & 1u)) >> 16;
    return (unsigned short)r;
}

// Build combined bf16 weights wc[15][256][64] in streaming combine order:
// slot: 0=d1t, 1=d1_0, 2=M0, 3=d1_1, 4=M1, 5=M2, 6=d1_2, 7=M3, 8=M4, 9=M5,
//       10=d1_3, 11=M6, 12=M7, 13=M8, 14=M9   (M_p = dn_w2[p] * dn_w1[p][None,:])
__global__ void build_weights(const float* __restrict__ d1t_w,
                              const float* __restrict__ d1_w,
                              const float* __restrict__ dn_w1,
                              const float* __restrict__ dn_w2,
                              unsigned short* __restrict__ wc) {
    int idx = blockIdx.x * blockDim.x + threadIdx.x;
    if (idx >= NMAT * OUTF * INF) return;
    int slot = idx / (OUTF * INF);
    int rem  = idx - slot * (OUTF * INF);   // o*64 + i
    int i    = rem & (INF - 1);

    const signed char kind[NMAT] = {0,1,2,1,2,2,1,2,2,2,1,2,2,2,2};
    const signed char sidx[NMAT] = {0,0,0,1,1,2,2,3,4,5,3,6,7,8,9};

    int k = kind[slot], si = sidx[slot];
    float v;
    if (k == 0)      v = d1t_w[rem];
    else if (k == 1) v = d1_w[si * OUTF * INF + rem];
    else             v = dn_w2[si * OUTF * INF + rem] * dn_w1[si * INF + i];
    wc[idx] = f2bf(v);
}

// Register-resident weights: each wave owns a fixed 16-col strip and holds all
// 15 B-fragments (120 VGPR) for the whole kernel; loops over 32-row blocks.
// No per-iteration weight loads -> no L2 latency chain.
__global__ __launch_bounds__(256) void taylor_kernel(
    const float* __restrict__ x, const float* __restrict__ d0,
    const unsigned short* __restrict__ wc, float* __restrict__ out)
{
    const int lane = threadIdx.x & 63;
    const int wave = threadIdx.x >> 6;      // 0..3
    const int l15  = lane & 15;
    const int g    = lane >> 4;             // k-group 0..3
    const int cg   = blockIdx.x & 3;        // col-group (64 cols)
    const int rc   = blockIdx.x >> 2;       // row-chunk (RPB rows)
    const int col  = cg * 64 + wave * 16 + l15;

    // One-time B load: 15 mats x 2 k-slices, 8 bf16 each = 120 VGPR
    bf16x8 b[NMAT][2];
#pragma unroll
    for (int w = 0; w < NMAT; ++w) {
        const unsigned short* wp = wc + ((size_t)w * OUTF + col) * INF + g * 8;
#pragma unroll
        for (int s = 0; s < 2; ++s)
            b[w][s] = *(const bf16x8*)(wp + s * 32);
    }
    const float d0v = d0[col];

    // per-pass combine op: 0 = res=d0+y, 1 = tmp=y, 2 = tmp*=y, 3 = tmp*=y; res+=tmp
    constexpr int OPS[NMAT] = {0,1,3,1,2,3,1,2,2,3,1,2,2,2,3};
    const size_t row0 = (size_t)rc * RPB;

    f32x4 pre[8];
    auto loadA = [&](int it) {
#pragma unroll
        for (int rf = 0; rf < 2; ++rf) {
            const float* xp = x + (row0 + (size_t)it * 32 + rf * 16 + l15) * INF + g * 8;
#pragma unroll
            for (int s = 0; s < 2; ++s) {
                pre[rf * 4 + s * 2 + 0] = *(const f32x4*)(xp + s * 32);
                pre[rf * 4 + s * 2 + 1] = *(const f32x4*)(xp + s * 32 + 4);
            }
        }
    };

    loadA(0);

#pragma unroll 1
    for (int it = 0; it < RPB / 32; ++it) {
        // convert prefetched x to bf16 A-fragments
        bf16x8 a[2][2];
#pragma unroll
        for (int rf = 0; rf < 2; ++rf)
#pragma unroll
            for (int s = 0; s < 2; ++s) {
                f32x4 v0 = pre[rf * 4 + s * 2], v1 = pre[rf * 4 + s * 2 + 1];
                bf16x8 fr;
#pragma unroll
                for (int j = 0; j < 4; ++j) { fr[j] = (__bf16)v0[j]; fr[4 + j] = (__bf16)v1[j]; }
                a[rf][s] = fr;
            }
        // issue next iteration's x loads; they fly under the MFMA/VALU below
        if (it + 1 < RPB / 32) loadA(it + 1);

        f32x4 res[2], tmp[2];
#pragma unroll
        for (int w = 0; w < NMAT; ++w) {
#pragma unroll
            for (int rf = 0; rf < 2; ++rf) {
                f32x4 y = {0.f, 0.f, 0.f, 0.f};
                y = __builtin_amdgcn_mfma_f32_16x16x32_bf16(a[rf][0], b[w][0], y, 0, 0, 0);
                y = __builtin_amdgcn_mfma_f32_16x16x32_bf16(a[rf][1], b[w][1], y, 0, 0, 0);
                if (OPS[w] == 0) {
                    f32x4 t = y;
#pragma unroll
                    for (int j = 0; j < 4; ++j) t[j] += d0v;
                    res[rf] = t;
                } else if (OPS[w] == 1) {
                    tmp[rf] = y;
                } else {
                    tmp[rf] = tmp[rf] * y;
                    if (OPS[w] == 3) res[rf] = res[rf] + tmp[rf];
                }
            }
        }

        // C layout: row = (lane>>4)*4 + r, col = lane&15
        const size_t rbase = row0 + (size_t)it * 32;
#pragma unroll
        for (int rf = 0; rf < 2; ++rf) {
            const size_t r0 = rbase + rf * 16 + g * 4;
#pragma unroll
            for (int r = 0; r < 4; ++r)
                out[(r0 + r) * OUTF + col] = res[rf][r];
        }
    }
}

extern "C" void kernel_launch(void* const* d_in, const int* in_sizes, int n_in,
                              void* d_out, int out_size, void* d_ws, size_t ws_size,
                              hipStream_t stream) {
    const float* x    = (const float*)d_in[0];
    const float* d0   = (const float*)d_in[1];
    const float* d1t  = (const float*)d_in[2];
    const float* d1w  = (const float*)d_in[3];
    const float* dnw1 = (const float*)d_in[4];
    const float* dnw2 = (const float*)d_in[5];
    unsigned short* wc = (unsigned short*)d_ws;   // 15*256*64*2 = 480 KiB
    float* out = (float*)d_out;

    build_weights<<<(NMAT * OUTF * INF + 255) / 256, 256, 0, stream>>>(d1t, d1w, dnw1, dnw2, wc);
    taylor_kernel<<<4 * (BATCH / RPB), 256, 0, stream>>>(x, d0, wc, out);
}